// Round 1
// baseline (1381.896 us; speedup 1.0000x reference)
//
#include <hip/hip_runtime.h>
#include <hip/hip_bf16.h>

typedef __hip_bfloat16 bf16;

struct __align__(8) bf16x4 { bf16 x, y, z, w; };

__device__ __forceinline__ float b2f(bf16 v) { return __bfloat162float(v); }
__device__ __forceinline__ bf16  f2b(float v) { return __float2bfloat16(v); }

// Problem constants: B=8, C=512, H=W=64 -> N=4096, HEADS=4, d=128, GROUPS=32
#define NSP 4096          // spatial n = H*W
#define CCH 512           // channels
#define NBATCH 8
#define CPG 16            // channels per group (512/32)
#define GN_ELEMS 65536    // CPG * NSP per (b, group)

// ---------------------------------------------------------------------------
// Kernel 1: GroupNorm -> bf16.  One block per (b, group) = 256 blocks.
// ---------------------------------------------------------------------------
__global__ __launch_bounds__(256) void gn_kernel(const float* __restrict__ x,
                                                 const float* __restrict__ gw,
                                                 const float* __restrict__ gb,
                                                 bf16* __restrict__ hn) {
    int blk = blockIdx.x;
    int b = blk >> 5, g = blk & 31;
    size_t base = ((size_t)(b * CCH + g * CPG)) * NSP;   // 65536 contiguous floats
    const float4* xp4 = (const float4*)(x + base);
    int t = threadIdx.x;

    float s = 0.f, s2 = 0.f;
    for (int i = t; i < GN_ELEMS / 4; i += 256) {
        float4 v = xp4[i];
        s  += v.x + v.y + v.z + v.w;
        s2 += v.x * v.x + v.y * v.y + v.z * v.z + v.w * v.w;
    }
    // wave reduce (wave = 64)
    for (int off = 32; off > 0; off >>= 1) {
        s  += __shfl_down(s, off);
        s2 += __shfl_down(s2, off);
    }
    __shared__ float red[8];
    int wid = t >> 6, lid = t & 63;
    if (lid == 0) { red[wid] = s; red[wid + 4] = s2; }
    __syncthreads();
    __shared__ float stats[2];
    if (t == 0) {
        float ts  = red[0] + red[1] + red[2] + red[3];
        float ts2 = red[4] + red[5] + red[6] + red[7];
        float mean = ts * (1.f / GN_ELEMS);
        float var  = ts2 * (1.f / GN_ELEMS) - mean * mean;
        stats[0] = mean;
        stats[1] = rsqrtf(var + 1e-5f);
    }
    __syncthreads();
    float mean = stats[0], rstd = stats[1];

    bf16x4* op = (bf16x4*)(hn + base);
    for (int i = t; i < GN_ELEMS / 4; i += 256) {
        int c = g * CPG + (i >> 10);            // (i*4)/4096
        float w = gw[c] * rstd;
        float bb = gb[c] - mean * w;
        float4 v = xp4[i];
        bf16x4 o;
        o.x = f2b(v.x * w + bb);
        o.y = f2b(v.y * w + bb);
        o.z = f2b(v.z * w + bb);
        o.w = f2b(v.w * w + bb);
        op[i] = o;
    }
}

// ---------------------------------------------------------------------------
// Generic batched GEMM: out[bz, m, n] = sum_k A[m,k] * X[bz, k, n] (+bias[m])
// (+resid, fp32 out) — A fp32 row-major, X bf16 (row stride NSP).
// Tile 64x64, BK=16, 256 threads, 4x4 micro-tile.
// RESID=false -> bf16 out; RESID=true -> fp32 out with residual add.
// ---------------------------------------------------------------------------
template <bool RESID>
__global__ __launch_bounds__(256) void gemm_kernel(const float* __restrict__ A,
                                                   const bf16* __restrict__ X,
                                                   const float* __restrict__ bias,
                                                   const float* __restrict__ resid,
                                                   void* __restrict__ out,
                                                   int K, size_t xStride, size_t outStride) {
    __shared__ float sA[16][64];   // [k][m]
    __shared__ float sX[16][64];   // [k][n]
    int t = threadIdx.x;
    int tx = t & 15, ty = t >> 4;
    int n0 = blockIdx.x * 64, m0 = blockIdx.y * 64;
    int bz = blockIdx.z;
    const bf16* Xb = X + xStride * bz;

    float acc[4][4] = {};
    int la_row = t >> 2;            // 0..63 (m)
    int la_k   = (t & 3) * 4;       // 0,4,8,12
    int lx_row = t >> 4;            // 0..15 (k)
    int lx_col = (t & 15) * 4;      // 0..60 (n)

    for (int k0 = 0; k0 < K; k0 += 16) {
        float4 av = *(const float4*)&A[(size_t)(m0 + la_row) * K + k0 + la_k];
        bf16x4 xv = *(const bf16x4*)&Xb[(size_t)(k0 + lx_row) * NSP + n0 + lx_col];
        __syncthreads();
        sA[la_k + 0][la_row] = av.x;
        sA[la_k + 1][la_row] = av.y;
        sA[la_k + 2][la_row] = av.z;
        sA[la_k + 3][la_row] = av.w;
        sX[lx_row][lx_col + 0] = b2f(xv.x);
        sX[lx_row][lx_col + 1] = b2f(xv.y);
        sX[lx_row][lx_col + 2] = b2f(xv.z);
        sX[lx_row][lx_col + 3] = b2f(xv.w);
        __syncthreads();
#pragma unroll
        for (int k = 0; k < 16; ++k) {
            float a[4], bx[4];
#pragma unroll
            for (int i = 0; i < 4; ++i) a[i] = sA[k][ty * 4 + i];
#pragma unroll
            for (int j = 0; j < 4; ++j) bx[j] = sX[k][tx * 4 + j];
#pragma unroll
            for (int i = 0; i < 4; ++i)
#pragma unroll
                for (int j = 0; j < 4; ++j) acc[i][j] += a[i] * bx[j];
        }
    }

#pragma unroll
    for (int i = 0; i < 4; ++i) {
        int m = m0 + ty * 4 + i;
        float bv = bias[m];
        size_t o = (size_t)bz * outStride + (size_t)m * NSP + n0 + tx * 4;
        if constexpr (RESID) {
            float4 r = *(const float4*)&resid[o];
            float4 ov;
            ov.x = acc[i][0] + bv + r.x;
            ov.y = acc[i][1] + bv + r.y;
            ov.z = acc[i][2] + bv + r.z;
            ov.w = acc[i][3] + bv + r.w;
            *(float4*)((float*)out + o) = ov;
        } else {
            bf16x4 ov;
            ov.x = f2b(acc[i][0] + bv);
            ov.y = f2b(acc[i][1] + bv);
            ov.z = f2b(acc[i][2] + bv);
            ov.w = f2b(acc[i][3] + bv);
            *(bf16x4*)((bf16*)out + o) = ov;
        }
    }
}

// ---------------------------------------------------------------------------
// Kernel 3a: S[bh, d, e] += sum_{n in chunk} q[d,n]*k[e,n]  (split-K atomics)
// grid (16 k-chunks of 256, 32 bh), 256 threads, 8x8 micro-tile.
// ---------------------------------------------------------------------------
__global__ __launch_bounds__(256) void qk_kernel(const bf16* __restrict__ qkv,
                                                 float* __restrict__ P) {
    int kc = blockIdx.x;
    int bh = blockIdx.y;
    int b = bh >> 2, h = bh & 3;
    const bf16* q  = qkv + ((size_t)b * 1536 + h * 128) * NSP;
    const bf16* kk = qkv + ((size_t)b * 1536 + 512 + h * 128) * NSP;
    int n_base = kc * 256;

    __shared__ float sQ[128][33];
    __shared__ float sK[128][33];
    int t = threadIdx.x;
    int tx = t & 15, ty = t >> 4;
    float acc[8][8] = {};
    int lrow = t >> 3;            // 0..31
    int lcol = (t & 7) * 4;       // 0..28

    for (int ns = 0; ns < 256; ns += 32) {
        __syncthreads();
#pragma unroll
        for (int r = 0; r < 4; ++r) {
            int row = lrow + r * 32;
            bf16x4 qv = *(const bf16x4*)&q[(size_t)row * NSP + n_base + ns + lcol];
            bf16x4 kv = *(const bf16x4*)&kk[(size_t)row * NSP + n_base + ns + lcol];
            sQ[row][lcol + 0] = b2f(qv.x);
            sQ[row][lcol + 1] = b2f(qv.y);
            sQ[row][lcol + 2] = b2f(qv.z);
            sQ[row][lcol + 3] = b2f(qv.w);
            sK[row][lcol + 0] = b2f(kv.x);
            sK[row][lcol + 1] = b2f(kv.y);
            sK[row][lcol + 2] = b2f(kv.z);
            sK[row][lcol + 3] = b2f(kv.w);
        }
        __syncthreads();
#pragma unroll 8
        for (int n = 0; n < 32; ++n) {
            float a[8], bv[8];
#pragma unroll
            for (int i = 0; i < 8; ++i) a[i] = sQ[ty * 8 + i][n];
#pragma unroll
            for (int j = 0; j < 8; ++j) bv[j] = sK[tx * 8 + j][n];
#pragma unroll
            for (int i = 0; i < 8; ++i)
#pragma unroll
                for (int j = 0; j < 8; ++j) acc[i][j] += a[i] * bv[j];
        }
    }
    float* Pp = P + (size_t)bh * 16384;
#pragma unroll
    for (int i = 0; i < 8; ++i)
#pragma unroll
        for (int j = 0; j < 8; ++j)
            atomicAdd(&Pp[(size_t)(ty * 8 + i) * 128 + tx * 8 + j], acc[i][j]);
}

// ---------------------------------------------------------------------------
// Kernel 3b: row softmax over e (128), with 1/sqrt(d) scale. One row/block.
// ---------------------------------------------------------------------------
__global__ __launch_bounds__(128) void softmax_kernel(float* __restrict__ P) {
    int row = blockIdx.x;          // 0..4095 (bh*128 + d)
    float* p = P + (size_t)row * 128;
    int t = threadIdx.x;
    float v = p[t] * 0.08838834764831845f;   // 128^-0.5
    float m = v;
    for (int off = 32; off > 0; off >>= 1) m = fmaxf(m, __shfl_down(m, off));
    __shared__ float sm[2];
    if ((t & 63) == 0) sm[t >> 6] = m;
    __syncthreads();
    m = fmaxf(sm[0], sm[1]);
    float e = __expf(v - m);
    float s = e;
    for (int off = 32; off > 0; off >>= 1) s += __shfl_down(s, off);
    __shared__ float ss[2];
    if ((t & 63) == 0) ss[t >> 6] = s;
    __syncthreads();
    s = ss[0] + ss[1];
    p[t] = e / s;
}

// ---------------------------------------------------------------------------
// Kernel 3c: att[b, h*128+d, n] = sum_e P[bh,d,e] * v[e,n].  Tiled like gemm.
// grid (64 n-tiles, 2 m-tiles, 32 bh)
// ---------------------------------------------------------------------------
__global__ __launch_bounds__(256) void pv_kernel(const float* __restrict__ P,
                                                 const bf16* __restrict__ qkv,
                                                 bf16* __restrict__ att) {
    int z = blockIdx.z;
    int b = z >> 2, h = z & 3;
    const float* A = P + (size_t)z * 16384;                         // 128x128
    const bf16* V = qkv + ((size_t)b * 1536 + 1024 + h * 128) * NSP;
    bf16* outp = att + ((size_t)b * CCH + h * 128) * NSP;

    __shared__ float sA[16][64];
    __shared__ float sX[16][64];
    int t = threadIdx.x;
    int tx = t & 15, ty = t >> 4;
    int n0 = blockIdx.x * 64, m0 = blockIdx.y * 64;
    float acc[4][4] = {};
    int la_row = t >> 2, la_k = (t & 3) * 4;
    int lx_row = t >> 4, lx_col = (t & 15) * 4;

    for (int k0 = 0; k0 < 128; k0 += 16) {
        float4 av = *(const float4*)&A[(size_t)(m0 + la_row) * 128 + k0 + la_k];
        bf16x4 xv = *(const bf16x4*)&V[(size_t)(k0 + lx_row) * NSP + n0 + lx_col];
        __syncthreads();
        sA[la_k + 0][la_row] = av.x;
        sA[la_k + 1][la_row] = av.y;
        sA[la_k + 2][la_row] = av.z;
        sA[la_k + 3][la_row] = av.w;
        sX[lx_row][lx_col + 0] = b2f(xv.x);
        sX[lx_row][lx_col + 1] = b2f(xv.y);
        sX[lx_row][lx_col + 2] = b2f(xv.z);
        sX[lx_row][lx_col + 3] = b2f(xv.w);
        __syncthreads();
#pragma unroll
        for (int k = 0; k < 16; ++k) {
            float a[4], bx[4];
#pragma unroll
            for (int i = 0; i < 4; ++i) a[i] = sA[k][ty * 4 + i];
#pragma unroll
            for (int j = 0; j < 4; ++j) bx[j] = sX[k][tx * 4 + j];
#pragma unroll
            for (int i = 0; i < 4; ++i)
#pragma unroll
                for (int j = 0; j < 4; ++j) acc[i][j] += a[i] * bx[j];
        }
    }
#pragma unroll
    for (int i = 0; i < 4; ++i) {
        int m = m0 + ty * 4 + i;
        size_t o = (size_t)m * NSP + n0 + tx * 4;
        bf16x4 ov;
        ov.x = f2b(acc[i][0]);
        ov.y = f2b(acc[i][1]);
        ov.z = f2b(acc[i][2]);
        ov.w = f2b(acc[i][3]);
        *(bf16x4*)&outp[o] = ov;
    }
}

// ---------------------------------------------------------------------------
extern "C" void kernel_launch(void* const* d_in, const int* in_sizes, int n_in,
                              void* d_out, int out_size, void* d_ws, size_t ws_size,
                              hipStream_t stream) {
    const float* x      = (const float*)d_in[0];
    const float* gn_w   = (const float*)d_in[1];
    const float* gn_b   = (const float*)d_in[2];
    const float* qkv_w  = (const float*)d_in[3];
    const float* qkv_b  = (const float*)d_in[4];
    const float* proj_w = (const float*)d_in[5];
    const float* proj_b = (const float*)d_in[6];
    float* out = (float*)d_out;

    char* ws = (char*)d_ws;
    bf16* hn   = (bf16*)ws;                              // B*C*N bf16 = 33.55 MB
    bf16* qkvp = (bf16*)(ws + 33554432);                 // 3*B*C*N bf16 = 100.66 MB
    float* P   = (float*)(ws + 134217728);               // 32*128*128 fp32 = 2 MB
    bf16* att  = hn;                                     // reuse (hn dead after QKV GEMM)

    hipMemsetAsync(P, 0, (size_t)32 * 128 * 128 * sizeof(float), stream);

    gn_kernel<<<256, 256, 0, stream>>>(x, gn_w, gn_b, hn);

    // QKV: A=(1536x512), X=hn (512x4096 per b), out=qkv (1536x4096 per b)
    gemm_kernel<false><<<dim3(64, 24, 8), 256, 0, stream>>>(
        qkv_w, hn, qkv_b, nullptr, qkvp, 512, (size_t)512 * NSP, (size_t)1536 * NSP);

    qk_kernel<<<dim3(16, 32), 256, 0, stream>>>(qkvp, P);
    softmax_kernel<<<4096, 128, 0, stream>>>(P);
    pv_kernel<<<dim3(64, 2, 32), 256, 0, stream>>>(P, qkvp, att);

    // Proj + bias + residual: A=(512x512), X=att, out fp32
    gemm_kernel<true><<<dim3(64, 8, 8), 256, 0, stream>>>(
        proj_w, att, proj_b, x, out, 512, (size_t)512 * NSP, (size_t)512 * NSP);
}

// Round 2
// 376.846 us; speedup vs baseline: 3.6670x; 3.6670x over previous
//
#include <hip/hip_runtime.h>
#include <hip/hip_bf16.h>

typedef __hip_bfloat16 bf16;
typedef __bf16 v8bf __attribute__((ext_vector_type(8)));
typedef float  v4f  __attribute__((ext_vector_type(4)));

struct __align__(8) bf16x4 { bf16 x, y, z, w; };

__device__ __forceinline__ bf16 f2b(float v) { return __float2bfloat16(v); }

// B=8, C=512, H=W=64 -> N=4096, HEADS=4, d=128, GROUPS=32
#define NSP 4096
#define CCH 512

// ---------------------------------------------------------------------------
// GN pass 1: per-(b,group) mean/rstd. 256 blocks.
// ---------------------------------------------------------------------------
__global__ __launch_bounds__(256) void gn_stats_kernel(const float* __restrict__ x,
                                                       float* __restrict__ stats) {
    int blk = blockIdx.x;
    int b = blk >> 5, g = blk & 31;
    size_t base = ((size_t)(b * CCH + g * 16)) * NSP;     // 65536 floats
    const float4* xp4 = (const float4*)(x + base);
    int t = threadIdx.x;
    float s = 0.f, s2 = 0.f;
    for (int i = t; i < 16384; i += 256) {
        float4 v = xp4[i];
        s  += v.x + v.y + v.z + v.w;
        s2 += v.x * v.x + v.y * v.y + v.z * v.z + v.w * v.w;
    }
    for (int off = 32; off > 0; off >>= 1) {
        s  += __shfl_down(s, off);
        s2 += __shfl_down(s2, off);
    }
    __shared__ float red[8];
    int wid = t >> 6, lid = t & 63;
    if (lid == 0) { red[wid] = s; red[wid + 4] = s2; }
    __syncthreads();
    if (t == 0) {
        float ts  = red[0] + red[1] + red[2] + red[3];
        float ts2 = red[4] + red[5] + red[6] + red[7];
        float mean = ts * (1.f / 65536.f);
        float var  = ts2 * (1.f / 65536.f) - mean * mean;
        stats[blk * 2]     = mean;
        stats[blk * 2 + 1] = rsqrtf(var + 1e-5f);
    }
}

// ---------------------------------------------------------------------------
// GN pass 2: normalize + transpose to n-major hnT[b][n][c] (bf16).
// Tile 64c x 64n via LDS. grid (64 n-tiles, 8 c-tiles, 8 b).
// ---------------------------------------------------------------------------
__global__ __launch_bounds__(256) void gn_norm_t_kernel(const float* __restrict__ x,
                                                        const float* __restrict__ gw,
                                                        const float* __restrict__ gb,
                                                        const float* __restrict__ stats,
                                                        bf16* __restrict__ hnT) {
    __shared__ float sT[64][65];
    int n0 = blockIdx.x * 64, c0 = blockIdx.y * 64, b = blockIdx.z;
    int t = threadIdx.x;
    int cl = t >> 4, nl4 = (t & 15) << 2;
#pragma unroll
    for (int it = 0; it < 4; ++it) {
        int crow = cl + it * 16;
        int c = c0 + crow;
        int bg = b * 32 + (c >> 4);
        float mean = stats[bg * 2], rstd = stats[bg * 2 + 1];
        float wsc = gw[c] * rstd;
        float bb  = gb[c] - mean * wsc;
        float4 v = *(const float4*)&x[((long)b * CCH + c) * NSP + n0 + nl4];
        sT[crow][nl4 + 0] = v.x * wsc + bb;
        sT[crow][nl4 + 1] = v.y * wsc + bb;
        sT[crow][nl4 + 2] = v.z * wsc + bb;
        sT[crow][nl4 + 3] = v.w * wsc + bb;
    }
    __syncthreads();
    int nl = t >> 4, cl4 = (t & 15) << 2;
#pragma unroll
    for (int it = 0; it < 4; ++it) {
        int nrow = nl + it * 16;
        bf16x4 ov = { f2b(sT[cl4 + 0][nrow]), f2b(sT[cl4 + 1][nrow]),
                      f2b(sT[cl4 + 2][nrow]), f2b(sT[cl4 + 3][nrow]) };
        *(bf16x4*)&hnT[((long)b * NSP + n0 + nrow) * CCH + c0 + cl4] = ov;
    }
}

// ---------------------------------------------------------------------------
// Shared MFMA GEMM core: 128x128 tile, BK=32, 256 threads (4 waves 2x2).
// Both operand tiles are [128 rows][32 k] with k contiguous in source.
// A source always bf16; B source bf16 or fp32 (converted during staging).
// acc[i][j]: wave subtile (i=row, j=col) 16x16.
// ---------------------------------------------------------------------------
template <bool BF32>
__device__ __forceinline__ void gemm_core(const bf16* __restrict__ Asrc, long astride,
                                          const void* __restrict__ Bsrc, long bstride,
                                          int K, v4f acc[4][4],
                                          __bf16* sA, __bf16* sB) {
    int t = threadIdx.x;
    int lane = t & 63, wv = t >> 6;
    int wr = wv >> 1, wc = wv & 1;
    int lq = lane & 15, quad = lane >> 4;
    int srow = t >> 1, soff = (t & 1) << 4;
    const __bf16* aBase = sA + (wr * 64) * 32;
    const __bf16* bBase = sB + (wc * 64) * 32;

    for (int k0 = 0; k0 < K; k0 += 32) {
        const bf16* ap = Asrc + (long)srow * astride + k0 + soff;
        v8bf aa0 = *(const v8bf*)(const void*)ap;
        v8bf aa1 = *(const v8bf*)(const void*)(ap + 8);
        v8bf bb0, bb1;
        if constexpr (BF32) {
            const float* bp = (const float*)Bsrc + (long)srow * bstride + k0 + soff;
            float4 f0 = *(const float4*)(bp + 0);
            float4 f1 = *(const float4*)(bp + 4);
            float4 f2 = *(const float4*)(bp + 8);
            float4 f3 = *(const float4*)(bp + 12);
            bb0[0] = (__bf16)f0.x; bb0[1] = (__bf16)f0.y; bb0[2] = (__bf16)f0.z; bb0[3] = (__bf16)f0.w;
            bb0[4] = (__bf16)f1.x; bb0[5] = (__bf16)f1.y; bb0[6] = (__bf16)f1.z; bb0[7] = (__bf16)f1.w;
            bb1[0] = (__bf16)f2.x; bb1[1] = (__bf16)f2.y; bb1[2] = (__bf16)f2.z; bb1[3] = (__bf16)f2.w;
            bb1[4] = (__bf16)f3.x; bb1[5] = (__bf16)f3.y; bb1[6] = (__bf16)f3.z; bb1[7] = (__bf16)f3.w;
        } else {
            const bf16* bp = (const bf16*)Bsrc + (long)srow * bstride + k0 + soff;
            bb0 = *(const v8bf*)(const void*)bp;
            bb1 = *(const v8bf*)(const void*)(bp + 8);
        }
        __syncthreads();   // prior-iteration LDS reads done
        *(v8bf*)(sA + srow * 32 + soff)     = aa0;
        *(v8bf*)(sA + srow * 32 + soff + 8) = aa1;
        *(v8bf*)(sB + srow * 32 + soff)     = bb0;
        *(v8bf*)(sB + srow * 32 + soff + 8) = bb1;
        __syncthreads();
        v8bf a[4], bf[4];
#pragma unroll
        for (int i = 0; i < 4; ++i)
            a[i] = *(const v8bf*)(aBase + (i * 16 + lq) * 32 + quad * 8);
#pragma unroll
        for (int j = 0; j < 4; ++j)
            bf[j] = *(const v8bf*)(bBase + (j * 16 + lq) * 32 + quad * 8);
#pragma unroll
        for (int i = 0; i < 4; ++i)
#pragma unroll
            for (int j = 0; j < 4; ++j)
                acc[i][j] = __builtin_amdgcn_mfma_f32_16x16x32_bf16(a[i], bf[j], acc[i][j], 0, 0, 0);
    }
}

// ---------------------------------------------------------------------------
// QKV GEMM (swapped): D[n][o] = sum_k hnT[n][k] * Wqkv[o][k]  (+bias)
// q,k (o<1024) -> qkbuf[b][o][n]; v (o>=1024) -> vT[b][n][e].
// grid (32 n-tiles, 12 o-tiles, 8 b)
// ---------------------------------------------------------------------------
__global__ __launch_bounds__(256) void qkv_gemm_kernel(const bf16* __restrict__ hnT,
                                                       const float* __restrict__ qkv_w,
                                                       const float* __restrict__ qkv_b,
                                                       bf16* __restrict__ qkbuf,
                                                       bf16* __restrict__ vT) {
    __shared__ __align__(16) __bf16 sA[128 * 32];
    __shared__ __align__(16) __bf16 sB[128 * 32];
    int n0 = blockIdx.x * 128, o0 = blockIdx.y * 128, b = blockIdx.z;
    v4f acc[4][4] = {};
    gemm_core<true>(hnT + ((long)b * NSP + n0) * CCH, CCH,
                    qkv_w + (long)o0 * CCH, CCH, CCH, acc, sA, sB);
    int t = threadIdx.x, lane = t & 63, wv = t >> 6, wr = wv >> 1, wc = wv & 1;
    int lq = lane & 15, quad = lane >> 4;
#pragma unroll
    for (int j = 0; j < 4; ++j) {
        int o = o0 + wc * 64 + j * 16 + lq;
        float bias = qkv_b[o];
#pragma unroll
        for (int i = 0; i < 4; ++i) {
            int n = n0 + wr * 64 + i * 16 + quad * 4;
            v4f v = acc[i][j];
            if (o0 < 1024) {
                bf16x4 ov = { f2b(v[0] + bias), f2b(v[1] + bias),
                              f2b(v[2] + bias), f2b(v[3] + bias) };
                *(bf16x4*)&qkbuf[((long)b * 1024 + o) * NSP + n] = ov;
            } else {
#pragma unroll
                for (int r = 0; r < 4; ++r)
                    vT[((long)b * NSP + n + r) * CCH + (o - 1024)] = f2b(v[r] + bias);
            }
        }
    }
}

// ---------------------------------------------------------------------------
// QK^T split-K: P_part[s][bh][d][e] = sum_{n in split} q[d][n]*k[e][n]
// grid (8 splits, 32 bh)
// ---------------------------------------------------------------------------
__global__ __launch_bounds__(256) void qk_gemm_kernel(const bf16* __restrict__ qkbuf,
                                                      float* __restrict__ P_part) {
    __shared__ __align__(16) __bf16 sA[128 * 32];
    __shared__ __align__(16) __bf16 sB[128 * 32];
    int s = blockIdx.x, bh = blockIdx.y;
    int b = bh >> 2, h = bh & 3;
    const bf16* q  = qkbuf + ((long)b * 1024 + h * 128) * NSP + s * 512;
    const bf16* kk = qkbuf + ((long)b * 1024 + 512 + h * 128) * NSP + s * 512;
    v4f acc[4][4] = {};
    gemm_core<false>(q, NSP, kk, NSP, 512, acc, sA, sB);
    float* Pp = P_part + ((long)s * 32 + bh) * 16384;
    int t = threadIdx.x, lane = t & 63, wv = t >> 6, wr = wv >> 1, wc = wv & 1;
    int lq = lane & 15, quad = lane >> 4;
#pragma unroll
    for (int j = 0; j < 4; ++j) {
        int e = wc * 64 + j * 16 + lq;
#pragma unroll
        for (int i = 0; i < 4; ++i) {
            int d = wr * 64 + i * 16 + quad * 4;
            v4f v = acc[i][j];
#pragma unroll
            for (int r = 0; r < 4; ++r) Pp[(long)(d + r) * 128 + e] = v[r];
        }
    }
}

// ---------------------------------------------------------------------------
// Softmax: sum 8 partials, scale by d^-0.5, softmax over e, emit bf16 P.
// grid 4096 rows (bh*128+d), 128 threads.
// ---------------------------------------------------------------------------
__global__ __launch_bounds__(128) void softmax_kernel(const float* __restrict__ P_part,
                                                      bf16* __restrict__ Pb) {
    int row = blockIdx.x;
    int bh = row >> 7, d = row & 127;
    int t = threadIdx.x;
    float v = 0.f;
#pragma unroll
    for (int s = 0; s < 8; ++s)
        v += P_part[((long)s * 32 + bh) * 16384 + (long)d * 128 + t];
    v *= 0.08838834764831845f;
    float m = v;
    for (int off = 32; off > 0; off >>= 1) m = fmaxf(m, __shfl_down(m, off));
    __shared__ float sm[2];
    if ((t & 63) == 0) sm[t >> 6] = m;
    __syncthreads();
    m = fmaxf(sm[0], sm[1]);
    float e = __expf(v - m);
    float ssum = e;
    for (int off = 32; off > 0; off >>= 1) ssum += __shfl_down(ssum, off);
    __shared__ float ss[2];
    if ((t & 63) == 0) ss[t >> 6] = ssum;
    __syncthreads();
    ssum = ss[0] + ss[1];
    Pb[(long)row * 128 + t] = f2b(e / ssum);
}

// ---------------------------------------------------------------------------
// PV: attT[b][n][h*128+d] = sum_e P[d][e] * vT[n][e].  grid (32 n-tiles, 32 bh)
// ---------------------------------------------------------------------------
__global__ __launch_bounds__(256) void pv_gemm_kernel(const bf16* __restrict__ Pb,
                                                      const bf16* __restrict__ vT,
                                                      bf16* __restrict__ attT) {
    __shared__ __align__(16) __bf16 sA[128 * 32];
    __shared__ __align__(16) __bf16 sB[128 * 32];
    int n0 = blockIdx.x * 128, bh = blockIdx.y;
    int b = bh >> 2, h = bh & 3;
    v4f acc[4][4] = {};
    gemm_core<false>(Pb + (long)bh * 16384, 128,
                     vT + ((long)b * NSP + n0) * CCH + h * 128, CCH, 128, acc, sA, sB);
    int t = threadIdx.x, lane = t & 63, wv = t >> 6, wr = wv >> 1, wc = wv & 1;
    int lq = lane & 15, quad = lane >> 4;
#pragma unroll
    for (int j = 0; j < 4; ++j) {
        int n = n0 + wc * 64 + j * 16 + lq;
#pragma unroll
        for (int i = 0; i < 4; ++i) {
            int d = wr * 64 + i * 16 + quad * 4;
            v4f v = acc[i][j];
            bf16x4 ov = { f2b(v[0]), f2b(v[1]), f2b(v[2]), f2b(v[3]) };
            *(bf16x4*)&attT[((long)b * NSP + n) * CCH + h * 128 + d] = ov;
        }
    }
}

// ---------------------------------------------------------------------------
// Proj (swapped): out[b][c][n] = sum_k attT[n][k]*Wp[c][k] + bias[c] + x
// grid (32 n-tiles, 4 c-tiles, 8 b)
// ---------------------------------------------------------------------------
__global__ __launch_bounds__(256) void proj_gemm_kernel(const bf16* __restrict__ attT,
                                                        const float* __restrict__ proj_w,
                                                        const float* __restrict__ proj_b,
                                                        const float* __restrict__ x,
                                                        float* __restrict__ out) {
    __shared__ __align__(16) __bf16 sA[128 * 32];
    __shared__ __align__(16) __bf16 sB[128 * 32];
    int n0 = blockIdx.x * 128, c0 = blockIdx.y * 128, b = blockIdx.z;
    v4f acc[4][4] = {};
    gemm_core<true>(attT + ((long)b * NSP + n0) * CCH, CCH,
                    proj_w + (long)c0 * CCH, CCH, CCH, acc, sA, sB);
    int t = threadIdx.x, lane = t & 63, wv = t >> 6, wr = wv >> 1, wc = wv & 1;
    int lq = lane & 15, quad = lane >> 4;
#pragma unroll
    for (int j = 0; j < 4; ++j) {
        int c = c0 + wc * 64 + j * 16 + lq;
        float bias = proj_b[c];
#pragma unroll
        for (int i = 0; i < 4; ++i) {
            int n = n0 + wr * 64 + i * 16 + quad * 4;
            long idx = ((long)b * CCH + c) * NSP + n;
            float4 r = *(const float4*)&x[idx];
            v4f v = acc[i][j];
            float4 ov = { v[0] + bias + r.x, v[1] + bias + r.y,
                          v[2] + bias + r.z, v[3] + bias + r.w };
            *(float4*)&out[idx] = ov;
        }
    }
}

// ---------------------------------------------------------------------------
extern "C" void kernel_launch(void* const* d_in, const int* in_sizes, int n_in,
                              void* d_out, int out_size, void* d_ws, size_t ws_size,
                              hipStream_t stream) {
    const float* x      = (const float*)d_in[0];
    const float* gn_w   = (const float*)d_in[1];
    const float* gn_b   = (const float*)d_in[2];
    const float* qkv_w  = (const float*)d_in[3];
    const float* qkv_b  = (const float*)d_in[4];
    const float* proj_w = (const float*)d_in[5];
    const float* proj_b = (const float*)d_in[6];
    float* out = (float*)d_out;

    char* ws = (char*)d_ws;
    // region0 (33.5 MB) reused over time: hnT -> P_part -> attT
    bf16*  hnT    = (bf16*)ws;
    float* P_part = (float*)ws;                    // 8*32*128*128 fp32 = 16.8 MB
    bf16*  attT   = (bf16*)ws;
    bf16*  qkbuf  = (bf16*)(ws + 33554432);        // [b][1024][4096] bf16 = 67.1 MB
    bf16*  vT     = (bf16*)(ws + 100663296);       // [b][4096][512]  bf16 = 33.5 MB
    bf16*  Pb     = (bf16*)(ws + 134217728);       // 32*128*128 bf16 = 1 MB
    float* stats  = (float*)(ws + 135266304);      // 256*2 fp32

    gn_stats_kernel<<<256, 256, 0, stream>>>(x, stats);
    gn_norm_t_kernel<<<dim3(64, 8, 8), 256, 0, stream>>>(x, gn_w, gn_b, stats, hnT);
    qkv_gemm_kernel<<<dim3(32, 12, 8), 256, 0, stream>>>(hnT, qkv_w, qkv_b, qkbuf, vT);
    qk_gemm_kernel<<<dim3(8, 32), 256, 0, stream>>>(qkbuf, P_part);
    softmax_kernel<<<4096, 128, 0, stream>>>(P_part, Pb);
    pv_gemm_kernel<<<dim3(32, 32), 256, 0, stream>>>(Pb, vT, attT);
    proj_gemm_kernel<<<dim3(32, 4, 8), 256, 0, stream>>>(attT, proj_w, proj_b, x, out);
}

// Round 3
// 318.356 us; speedup vs baseline: 4.3407x; 1.1837x over previous
//
#include <hip/hip_runtime.h>
#include <hip/hip_bf16.h>

typedef __hip_bfloat16 bf16;
typedef __bf16 v8bf __attribute__((ext_vector_type(8)));
typedef float  v4f  __attribute__((ext_vector_type(4)));

struct __align__(8) bf16x4 { bf16 x, y, z, w; };

__device__ __forceinline__ bf16 f2b(float v) { return __float2bfloat16(v); }

// B=8, C=512, H=W=64 -> N=4096, HEADS=4, d=128, GROUPS=32
#define NSP 4096
#define CCH 512

// Async 16B global -> LDS (gfx950 direct-to-LDS, wave-uniform base + lane*16).
__device__ __forceinline__ void async_cp16(const bf16* g, __bf16* l) {
    __builtin_amdgcn_global_load_lds(
        (const __attribute__((address_space(1))) unsigned int*)(unsigned long long)g,
        (__attribute__((address_space(3))) unsigned int*)(unsigned int)(unsigned long long)l,
        16, 0, 0);
}

// ---------------------------------------------------------------------------
// Weight fp32 -> bf16 conversion (runs every launch; weights are re-restored).
// ---------------------------------------------------------------------------
__global__ __launch_bounds__(256) void wconv_kernel(const float* __restrict__ src,
                                                    bf16* __restrict__ dst, int n4) {
    int i = blockIdx.x * 256 + threadIdx.x;
    if (i < n4) {
        float4 v = ((const float4*)src)[i];
        bf16x4 o = { f2b(v.x), f2b(v.y), f2b(v.z), f2b(v.w) };
        ((bf16x4*)dst)[i] = o;
    }
}

// ---------------------------------------------------------------------------
// GN pass 1: per-(b,group) mean/rstd. 256 blocks.
// ---------------------------------------------------------------------------
__global__ __launch_bounds__(256) void gn_stats_kernel(const float* __restrict__ x,
                                                       float* __restrict__ stats) {
    int blk = blockIdx.x;
    int b = blk >> 5, g = blk & 31;
    size_t base = ((size_t)(b * CCH + g * 16)) * NSP;     // 65536 floats
    const float4* xp4 = (const float4*)(x + base);
    int t = threadIdx.x;
    float s = 0.f, s2 = 0.f;
    for (int i = t; i < 16384; i += 256) {
        float4 v = xp4[i];
        s  += v.x + v.y + v.z + v.w;
        s2 += v.x * v.x + v.y * v.y + v.z * v.z + v.w * v.w;
    }
    for (int off = 32; off > 0; off >>= 1) {
        s  += __shfl_down(s, off);
        s2 += __shfl_down(s2, off);
    }
    __shared__ float red[8];
    int wid = t >> 6, lid = t & 63;
    if (lid == 0) { red[wid] = s; red[wid + 4] = s2; }
    __syncthreads();
    if (t == 0) {
        float ts  = red[0] + red[1] + red[2] + red[3];
        float ts2 = red[4] + red[5] + red[6] + red[7];
        float mean = ts * (1.f / 65536.f);
        float var  = ts2 * (1.f / 65536.f) - mean * mean;
        stats[blk * 2]     = mean;
        stats[blk * 2 + 1] = rsqrtf(var + 1e-5f);
    }
}

// ---------------------------------------------------------------------------
// GN pass 2: normalize + transpose to n-major hnT[b][n][c] (bf16).
// ---------------------------------------------------------------------------
__global__ __launch_bounds__(256) void gn_norm_t_kernel(const float* __restrict__ x,
                                                        const float* __restrict__ gw,
                                                        const float* __restrict__ gb,
                                                        const float* __restrict__ stats,
                                                        bf16* __restrict__ hnT) {
    __shared__ float sT[64][65];
    int n0 = blockIdx.x * 64, c0 = blockIdx.y * 64, b = blockIdx.z;
    int t = threadIdx.x;
    int cl = t >> 4, nl4 = (t & 15) << 2;
#pragma unroll
    for (int it = 0; it < 4; ++it) {
        int crow = cl + it * 16;
        int c = c0 + crow;
        int bg = b * 32 + (c >> 4);
        float mean = stats[bg * 2], rstd = stats[bg * 2 + 1];
        float wsc = gw[c] * rstd;
        float bb  = gb[c] - mean * wsc;
        float4 v = *(const float4*)&x[((long)b * CCH + c) * NSP + n0 + nl4];
        sT[crow][nl4 + 0] = v.x * wsc + bb;
        sT[crow][nl4 + 1] = v.y * wsc + bb;
        sT[crow][nl4 + 2] = v.z * wsc + bb;
        sT[crow][nl4 + 3] = v.w * wsc + bb;
    }
    __syncthreads();
    int nl = t >> 4, cl4 = (t & 15) << 2;
#pragma unroll
    for (int it = 0; it < 4; ++it) {
        int nrow = nl + it * 16;
        bf16x4 ov = { f2b(sT[cl4 + 0][nrow]), f2b(sT[cl4 + 1][nrow]),
                      f2b(sT[cl4 + 2][nrow]), f2b(sT[cl4 + 3][nrow]) };
        *(bf16x4*)&hnT[((long)b * NSP + n0 + nrow) * CCH + c0 + cl4] = ov;
    }
}

// ---------------------------------------------------------------------------
// MFMA GEMM core (m97 structure): 128x128 tile, BK=32, 256 threads (4 waves
// 2x2). A/B tiles [128 rows][32 k], k contiguous in source, both bf16.
// Staging via global_load_lds dwordx4: per thread 4 async 16B issues per
// K-step, linear LDS layout (uniform base + lane*16 per wave).
// ---------------------------------------------------------------------------
__device__ __forceinline__ void gemm_core(const bf16* __restrict__ A, long as,
                                          const bf16* __restrict__ B, long bs,
                                          int K, v4f acc[4][4],
                                          __bf16* sA, __bf16* sB) {
    int t = threadIdx.x;
    int lane = t & 63, wv = t >> 6;
    int wr = wv >> 1, wc = wv & 1;
    int lq = lane & 15, quad = lane >> 4;
    int r0 = wv * 16 + (lane >> 2);      // staging row, issue 0
    int koff = (lane & 3) * 8;           // staging k offset (elements)
    __bf16* ldsA0 = sA + wv * 512 + lane * 8;
    __bf16* ldsA1 = ldsA0 + 2048;
    __bf16* ldsB0 = sB + wv * 512 + lane * 8;
    __bf16* ldsB1 = ldsB0 + 2048;
    const __bf16* aBase = sA + (wr * 64) * 32;
    const __bf16* bBase = sB + (wc * 64) * 32;

    for (int k0 = 0; k0 < K; k0 += 32) {
        __syncthreads();                 // prior-iteration LDS reads done
        async_cp16(A + (long)r0 * as + k0 + koff,        ldsA0);
        async_cp16(A + (long)(r0 + 64) * as + k0 + koff, ldsA1);
        async_cp16(B + (long)r0 * bs + k0 + koff,        ldsB0);
        async_cp16(B + (long)(r0 + 64) * bs + k0 + koff, ldsB1);
        __syncthreads();                 // vmcnt drained at barrier -> data visible
        v8bf a[4], bf[4];
#pragma unroll
        for (int i = 0; i < 4; ++i)
            a[i] = *(const v8bf*)(aBase + (i * 16 + lq) * 32 + quad * 8);
#pragma unroll
        for (int j = 0; j < 4; ++j)
            bf[j] = *(const v8bf*)(bBase + (j * 16 + lq) * 32 + quad * 8);
#pragma unroll
        for (int i = 0; i < 4; ++i)
#pragma unroll
            for (int j = 0; j < 4; ++j)
                acc[i][j] = __builtin_amdgcn_mfma_f32_16x16x32_bf16(a[i], bf[j], acc[i][j], 0, 0, 0);
    }
}

// ---------------------------------------------------------------------------
// QKV GEMM (swapped): D[n][o] = sum_k hnT[n][k] * Wqkv[o][k]  (+bias)
// q,k (o<1024) -> qkbuf[b][o][n]; v (o>=1024) -> vT[b][n][e].
// grid (32 n-tiles, 12 o-tiles, 8 b)
// ---------------------------------------------------------------------------
__global__ __launch_bounds__(256) void qkv_gemm_kernel(const bf16* __restrict__ hnT,
                                                       const bf16* __restrict__ qkv_wb,
                                                       const float* __restrict__ qkv_b,
                                                       bf16* __restrict__ qkbuf,
                                                       bf16* __restrict__ vT) {
    __shared__ __align__(16) __bf16 sA[128 * 32];
    __shared__ __align__(16) __bf16 sB[128 * 32];
    int n0 = blockIdx.x * 128, o0 = blockIdx.y * 128, b = blockIdx.z;
    v4f acc[4][4] = {};
    gemm_core(hnT + ((long)b * NSP + n0) * CCH, CCH,
              qkv_wb + (long)o0 * CCH, CCH, CCH, acc, sA, sB);
    int t = threadIdx.x, lane = t & 63, wv = t >> 6, wr = wv >> 1, wc = wv & 1;
    int lq = lane & 15, quad = lane >> 4;
#pragma unroll
    for (int j = 0; j < 4; ++j) {
        int o = o0 + wc * 64 + j * 16 + lq;
        float bias = qkv_b[o];
#pragma unroll
        for (int i = 0; i < 4; ++i) {
            int n = n0 + wr * 64 + i * 16 + quad * 4;
            v4f v = acc[i][j];
            if (o0 < 1024) {
                bf16x4 ov = { f2b(v[0] + bias), f2b(v[1] + bias),
                              f2b(v[2] + bias), f2b(v[3] + bias) };
                *(bf16x4*)&qkbuf[((long)b * 1024 + o) * NSP + n] = ov;
            } else {
#pragma unroll
                for (int r = 0; r < 4; ++r)
                    vT[((long)b * NSP + n + r) * CCH + (o - 1024)] = f2b(v[r] + bias);
            }
        }
    }
}

// ---------------------------------------------------------------------------
// QK^T split-K: P_part[s][bh][d][e] = sum_{n in split} q[d][n]*k[e][n]
// grid (8 splits, 32 bh)
// ---------------------------------------------------------------------------
__global__ __launch_bounds__(256) void qk_gemm_kernel(const bf16* __restrict__ qkbuf,
                                                      float* __restrict__ P_part) {
    __shared__ __align__(16) __bf16 sA[128 * 32];
    __shared__ __align__(16) __bf16 sB[128 * 32];
    int s = blockIdx.x, bh = blockIdx.y;
    int b = bh >> 2, h = bh & 3;
    const bf16* q  = qkbuf + ((long)b * 1024 + h * 128) * NSP + s * 512;
    const bf16* kk = qkbuf + ((long)b * 1024 + 512 + h * 128) * NSP + s * 512;
    v4f acc[4][4] = {};
    gemm_core(q, NSP, kk, NSP, 512, acc, sA, sB);
    float* Pp = P_part + ((long)s * 32 + bh) * 16384;
    int t = threadIdx.x, lane = t & 63, wv = t >> 6, wr = wv >> 1, wc = wv & 1;
    int lq = lane & 15, quad = lane >> 4;
#pragma unroll
    for (int j = 0; j < 4; ++j) {
        int e = wc * 64 + j * 16 + lq;
#pragma unroll
        for (int i = 0; i < 4; ++i) {
            int d = wr * 64 + i * 16 + quad * 4;
            v4f v = acc[i][j];
#pragma unroll
            for (int r = 0; r < 4; ++r) Pp[(long)(d + r) * 128 + e] = v[r];
        }
    }
}

// ---------------------------------------------------------------------------
// Softmax: sum 8 partials, scale by d^-0.5, softmax over e, emit bf16 P.
// ---------------------------------------------------------------------------
__global__ __launch_bounds__(128) void softmax_kernel(const float* __restrict__ P_part,
                                                      bf16* __restrict__ Pb) {
    int row = blockIdx.x;
    int bh = row >> 7, d = row & 127;
    int t = threadIdx.x;
    float v = 0.f;
#pragma unroll
    for (int s = 0; s < 8; ++s)
        v += P_part[((long)s * 32 + bh) * 16384 + (long)d * 128 + t];
    v *= 0.08838834764831845f;
    float m = v;
    for (int off = 32; off > 0; off >>= 1) m = fmaxf(m, __shfl_down(m, off));
    __shared__ float sm[2];
    if ((t & 63) == 0) sm[t >> 6] = m;
    __syncthreads();
    m = fmaxf(sm[0], sm[1]);
    float e = __expf(v - m);
    float ssum = e;
    for (int off = 32; off > 0; off >>= 1) ssum += __shfl_down(ssum, off);
    __shared__ float ss[2];
    if ((t & 63) == 0) ss[t >> 6] = ssum;
    __syncthreads();
    ssum = ss[0] + ss[1];
    Pb[(long)row * 128 + t] = f2b(e / ssum);
}

// ---------------------------------------------------------------------------
// PV: attT[b][n][h*128+d] = sum_e P[d][e] * vT[n][e].  grid (32 n-tiles, 32 bh)
// ---------------------------------------------------------------------------
__global__ __launch_bounds__(256) void pv_gemm_kernel(const bf16* __restrict__ Pb,
                                                      const bf16* __restrict__ vT,
                                                      bf16* __restrict__ attT) {
    __shared__ __align__(16) __bf16 sA[128 * 32];
    __shared__ __align__(16) __bf16 sB[128 * 32];
    int n0 = blockIdx.x * 128, bh = blockIdx.y;
    int b = bh >> 2, h = bh & 3;
    v4f acc[4][4] = {};
    gemm_core(Pb + (long)bh * 16384, 128,
              vT + ((long)b * NSP + n0) * CCH + h * 128, CCH, 128, acc, sA, sB);
    int t = threadIdx.x, lane = t & 63, wv = t >> 6, wr = wv >> 1, wc = wv & 1;
    int lq = lane & 15, quad = lane >> 4;
#pragma unroll
    for (int j = 0; j < 4; ++j) {
        int n = n0 + wc * 64 + j * 16 + lq;
#pragma unroll
        for (int i = 0; i < 4; ++i) {
            int d = wr * 64 + i * 16 + quad * 4;
            v4f v = acc[i][j];
            bf16x4 ov = { f2b(v[0]), f2b(v[1]), f2b(v[2]), f2b(v[3]) };
            *(bf16x4*)&attT[((long)b * NSP + n) * CCH + h * 128 + d] = ov;
        }
    }
}

// ---------------------------------------------------------------------------
// Proj (swapped): out[b][c][n] = sum_k attT[n][k]*Wp[c][k] + bias[c] + x
// grid (32 n-tiles, 4 c-tiles, 8 b)
// ---------------------------------------------------------------------------
__global__ __launch_bounds__(256) void proj_gemm_kernel(const bf16* __restrict__ attT,
                                                        const bf16* __restrict__ proj_wb,
                                                        const float* __restrict__ proj_b,
                                                        const float* __restrict__ x,
                                                        float* __restrict__ out) {
    __shared__ __align__(16) __bf16 sA[128 * 32];
    __shared__ __align__(16) __bf16 sB[128 * 32];
    int n0 = blockIdx.x * 128, c0 = blockIdx.y * 128, b = blockIdx.z;
    v4f acc[4][4] = {};
    gemm_core(attT + ((long)b * NSP + n0) * CCH, CCH,
              proj_wb + (long)c0 * CCH, CCH, CCH, acc, sA, sB);
    int t = threadIdx.x, lane = t & 63, wv = t >> 6, wr = wv >> 1, wc = wv & 1;
    int lq = lane & 15, quad = lane >> 4;
#pragma unroll
    for (int j = 0; j < 4; ++j) {
        int c = c0 + wc * 64 + j * 16 + lq;
        float bias = proj_b[c];
#pragma unroll
        for (int i = 0; i < 4; ++i) {
            int n = n0 + wr * 64 + i * 16 + quad * 4;
            long idx = ((long)b * CCH + c) * NSP + n;
            float4 r = *(const float4*)&x[idx];
            v4f v = acc[i][j];
            float4 ov = { v[0] + bias + r.x, v[1] + bias + r.y,
                          v[2] + bias + r.z, v[3] + bias + r.w };
            *(float4*)&out[idx] = ov;
        }
    }
}

// ---------------------------------------------------------------------------
extern "C" void kernel_launch(void* const* d_in, const int* in_sizes, int n_in,
                              void* d_out, int out_size, void* d_ws, size_t ws_size,
                              hipStream_t stream) {
    const float* x      = (const float*)d_in[0];
    const float* gn_w   = (const float*)d_in[1];
    const float* gn_b   = (const float*)d_in[2];
    const float* qkv_w  = (const float*)d_in[3];
    const float* qkv_b  = (const float*)d_in[4];
    const float* proj_w = (const float*)d_in[5];
    const float* proj_b = (const float*)d_in[6];
    float* out = (float*)d_out;

    char* ws = (char*)d_ws;
    // region0 (33.5 MB) reused over time: hnT -> P_part -> attT
    bf16*  hnT    = (bf16*)ws;
    float* P_part = (float*)ws;                    // 8*32*128*128 fp32 = 16.8 MB
    bf16*  attT   = (bf16*)ws;
    bf16*  qkbuf  = (bf16*)(ws + 33554432);        // [b][1024][4096] bf16 = 67.1 MB
    bf16*  vT     = (bf16*)(ws + 100663296);       // [b][4096][512]  bf16 = 33.5 MB
    bf16*  Pb     = (bf16*)(ws + 134217728);       // 32*128*128 bf16 = 1 MB
    float* stats  = (float*)(ws + 135266304);      // 256*2 fp32
    bf16*  qkv_wb = (bf16*)(ws + 135270400);       // 1536*512 bf16 = 1.5 MB
    bf16*  proj_wb= (bf16*)(ws + 136843264);       // 512*512 bf16 = 0.5 MB

    wconv_kernel<<<768, 256, 0, stream>>>(qkv_w, qkv_wb, 196608);
    wconv_kernel<<<256, 256, 0, stream>>>(proj_w, proj_wb, 65536);
    gn_stats_kernel<<<256, 256, 0, stream>>>(x, stats);
    gn_norm_t_kernel<<<dim3(64, 8, 8), 256, 0, stream>>>(x, gn_w, gn_b, stats, hnT);
    qkv_gemm_kernel<<<dim3(32, 12, 8), 256, 0, stream>>>(hnT, qkv_wb, qkv_b, qkbuf, vT);
    qk_gemm_kernel<<<dim3(8, 32), 256, 0, stream>>>(qkbuf, P_part);
    softmax_kernel<<<4096, 128, 0, stream>>>(P_part, Pb);
    pv_gemm_kernel<<<dim3(32, 32), 256, 0, stream>>>(Pb, vT, attT);
    proj_gemm_kernel<<<dim3(32, 4, 8), 256, 0, stream>>>(attT, proj_wb, proj_b, x, out);
}